// Round 8
// baseline (177.406 us; speedup 1.0000x reference)
//
#include <hip/hip_runtime.h>
#include <math.h>

#define S_ 4
#define C_ 384
#define H_ 96
#define W_ 96
#define B_ 8
#define M_ 64
#define HW_ (H_ * W_)
#define EPSV 1e-6f
#define BETA_V 0.3f
#define TEMP_V 0.07f

#define NB_A (S_ * C_)            // 1536 plane-sum blocks
#define NB_B (M_ * (C_ / 4))      // 6144 window blocks (round-3 form)
#define NB_PREP (NB_A + NB_B + 1)
#define REP_P 2                   // prep replication (measurement)

#define NSLICE 4                  // channel slices for score S1
#define CS (C_ / NSLICE)          // 96 channels per slice
#define NTILE (HW_ / 256)         // 36 pixel tiles per image
#define NB_S1 (B_ * NSLICE * NTILE)  // 1152
#define REP_S 5                   // score1 replication (measurement)
#define NB_S2 (B_ * HW_ / 256)       // 288

__device__ __forceinline__ float wave_sum(float v) {
#pragma unroll
    for (int o = 32; o; o >>= 1) v += __shfl_down(v, o, 64);
    return v;
}

__device__ __forceinline__ float block_sum(float v) {
    __shared__ float sm[4];
    int lane = threadIdx.x & 63;
    int wid = threadIdx.x >> 6;
    v = wave_sum(v);
    if (lane == 0) sm[wid] = v;
    __syncthreads();
    float r = sm[0] + sm[1] + sm[2] + sm[3];
    __syncthreads();
    return r;
}

// Fused prep (round-3 structure), replicated REP_P x in one dispatch.
// role A = per-(s,c) masked plane sums; role B = per-(anchor, 4-channel group)
// window sums; role C = fg mask total. Replicas redo identical work
// (idempotent identical writes - deterministic).
__global__ __launch_bounds__(256) void k_prep(const float* __restrict__ feats,
                                              const int* __restrict__ mask,
                                              const int* __restrict__ pos,
                                              const int* __restrict__ samp,
                                              const int* __restrict__ rad,
                                              float* __restrict__ partial,
                                              float* __restrict__ proto,
                                              float* __restrict__ msum_out,
                                              float* __restrict__ fg_out) {
    int bid = blockIdx.x;
    bid -= (bid / NB_PREP) * NB_PREP;  // replica fold
    int t = threadIdx.x;

    if (bid < NB_A) {
        // ---- role A
        int s = bid / C_;
        const float4* fp = (const float4*)(feats + (size_t)bid * HW_);
        const int4* mp = (const int4*)(mask + (size_t)s * HW_);
        float acc = 0.0f;
#pragma unroll
        for (int k = 0; k < HW_ / 4 / 256; ++k) {  // 9 iterations
            int i = t + k * 256;
            float4 f = fp[i];
            int4 m = mp[i];
            acc += f.x * (float)m.x + f.y * (float)m.y + f.z * (float)m.z + f.w * (float)m.w;
        }
        float tot = block_sum(acc);
        if (t == 0) partial[bid] = tot;
        return;
    }
    bid -= NB_A;
    if (bid < NB_B) {
        // ---- role B: one block per (anchor m, channel-group of 4)
        const int CG = C_ / 4;  // 96
        int m = bid / CG;
        int cg = bid % CG;
        int y = pos[2 * m + 0];
        int x = pos[2 * m + 1];
        int s = samp[m];
        int ri = rad[m];
        int r = (ri == 0) ? 4 : (ri == 1) ? 8 : 16;
        int y0 = max(y - r, 0), y1 = min(y + r + 1, H_);
        int x0 = max(x - r, 0), x1 = min(x + r + 1, W_);
        int ww = x1 - x0;
        int n = (y1 - y0) * ww;

        __shared__ float mwin[33 * 33];
        const int* mp = mask + (size_t)s * HW_;
        float macc = 0.0f;
        {
            int yy = t / ww;
            int xx = t - yy * ww;
            int dy = 256 / ww, dx = 256 - dy * ww;  // dx < ww
            for (int i = t; i < n; i += 256) {
                float mv = (float)mp[(y0 + yy) * W_ + x0 + xx];
                mwin[i] = mv;
                macc += mv;
                xx += dx; yy += dy;
                if (xx >= ww) { xx -= ww; ++yy; }
            }
        }
        float msumv = block_sum(macc);  // internal barrier publishes mwin
        if (cg == 0 && t == 0) msum_out[m] = msumv;
        float inv = 1.0f / (msumv + EPSV);

        int wid = t >> 6;
        int lane = t & 63;
        int c = cg * 4 + wid;
        const float* fp = feats + ((size_t)s * C_ + c) * HW_;
        float acc = 0.0f;
        {
            int yy = lane / ww;
            int xx = lane - yy * ww;
            int dy = 64 / ww, dx = 64 - dy * ww;
            for (int i = lane; i < n; i += 64) {
                acc += fp[(y0 + yy) * W_ + x0 + xx] * mwin[i];
                xx += dx; yy += dy;
                if (xx >= ww) { xx -= ww; ++yy; }
            }
        }
        acc = wave_sum(acc);
        if (lane == 0) proto[m * C_ + c] = acc * inv;
        return;
    }
    // ---- role C: fg = total mask sum
    const int4* mp4 = (const int4*)mask;
    float acc = 0.0f;
    for (int i = t; i < S_ * HW_ / 4; i += 256) {
        int4 m = mp4[i];
        acc += (float)(m.x + m.y + m.z + m.w);
    }
    float fg = block_sum(acc);
    if (t == 0) fg_out[0] = fg;
}

// Single block: combine into the final C-vector v.
__global__ __launch_bounds__(256) void k_finalize(const float* __restrict__ partial,
                                                  const float* __restrict__ msum,
                                                  const float* __restrict__ proto,
                                                  const float* __restrict__ fg_in,
                                                  float* __restrict__ v) {
    int tid = threadIdx.x;
    int wid = tid >> 6;
    int lane = tid & 63;

    float invfg = 1.0f / (fg_in[0] + EPSV);

    __shared__ float gv[C_];
    for (int c = tid; c < C_; c += 256) {
        float tv = 0.0f;
        for (int s = 0; s < S_; ++s) tv += partial[s * C_ + c];
        gv[c] = tv * invfg;
    }
    __syncthreads();

    float sq = 0.0f;
    for (int c = tid; c < C_; c += 256) sq += gv[c] * gv[c];
    float gn = block_sum(sq);
    gn = fmaxf(sqrtf(gn), 1e-12f);

    float wa = (tid < M_) ? msum[tid] : 0.0f;
    float T = block_sum(wa);
    float wb = (tid < M_) ? msum[tid] / (T + EPSV) : 0.0f;
    float wsum = block_sum(wb);

    __shared__ float pn[M_];
    for (int m = wid; m < M_; m += 4) {
        float a = 0.0f;
        for (int c = lane; c < C_; c += 64) {
            float p = proto[m * C_ + c];
            a += p * p;
        }
        a = wave_sum(a);
        if (lane == 0) pn[m] = fmaxf(sqrtf(a), 1e-12f);
    }
    __syncthreads();

    __shared__ float wq[M_];
    if (tid < M_) {
        float w = (msum[tid] / (T + EPSV)) / (wsum + EPSV);
        wq[tid] = w / pn[tid];
    }
    __syncthreads();

    for (int c = tid; c < C_; c += 256) {
        float vl = 0.0f;
        for (int m = 0; m < M_; ++m) vl += wq[m] * proto[m * C_ + c];
        v[c] = BETA_V * (gv[c] / gn) + (1.0f - BETA_V) * vl;
    }
}

// Score S1 (float4), replicated REP_S x in one dispatch (identical writes).
__global__ __launch_bounds__(256) void k_score1(const float* __restrict__ q,
                                                const float* __restrict__ v,
                                                float* __restrict__ wsd,
                                                float* __restrict__ wss) {
    int bid = blockIdx.x;
    bid -= (bid / NB_S1) * NB_S1;  // replica fold
    int tile = bid % NTILE;
    int bs = bid / NTILE;
    int sl = bs % NSLICE;
    int b = bs / NSLICE;

    int wid = threadIdx.x >> 6;
    int lane = threadIdx.x & 63;
    int p0 = tile * 256;

    const float4* qp = (const float4*)(q + (size_t)b * C_ * HW_ + p0);
    int c0 = sl * CS + wid * 24;

    float4 dot = {0.f, 0.f, 0.f, 0.f};
    float4 sq = {0.f, 0.f, 0.f, 0.f};
#pragma unroll 8
    for (int j = 0; j < 24; ++j) {
        int c = c0 + j;
        float4 f = qp[(size_t)c * (HW_ / 4) + lane];
        float vc = v[c];
        dot.x += f.x * vc; dot.y += f.y * vc; dot.z += f.z * vc; dot.w += f.w * vc;
        sq.x += f.x * f.x; sq.y += f.y * f.y; sq.z += f.z * f.z; sq.w += f.w * f.w;
    }

    __shared__ float4 sd[4][64];
    __shared__ float4 ss[4][64];
    sd[wid][lane] = dot;
    ss[wid][lane] = sq;
    __syncthreads();
    if (wid == 0) {
        float4 d = sd[0][lane];
        float4 s2 = ss[0][lane];
#pragma unroll
        for (int w = 1; w < 4; ++w) {
            float4 a = sd[w][lane];
            float4 b2 = ss[w][lane];
            d.x += a.x; d.y += a.y; d.z += a.z; d.w += a.w;
            s2.x += b2.x; s2.y += b2.y; s2.z += b2.z; s2.w += b2.w;
        }
        size_t base = ((size_t)(b * NSLICE + sl) * HW_ + p0) / 4;
        ((float4*)wsd)[base + lane] = d;
        ((float4*)wss)[base + lane] = s2;
    }
}

// Score S2: reduce NSLICE partials per pixel, write both logit planes.
__global__ __launch_bounds__(256) void k_score2(const float* __restrict__ wsd,
                                                const float* __restrict__ wss,
                                                float* __restrict__ out) {
    int px = blockIdx.x * 256 + threadIdx.x;  // < B_*HW_
    int b = px / HW_;
    int p = px - b * HW_;

    float d = 0.0f, s2 = 0.0f;
#pragma unroll
    for (int sl = 0; sl < NSLICE; ++sl) {
        size_t idx = (size_t)(b * NSLICE + sl) * HW_ + p;
        d += wsd[idx];
        s2 += wss[idx];
    }
    float sv = d / fmaxf(sqrtf(s2), 1e-12f);
    float o = sv / TEMP_V;
    float* ob = out + (size_t)b * 2 * HW_;
    ob[p] = -o;
    ob[HW_ + p] = o;
}

extern "C" void kernel_launch(void* const* d_in, const int* in_sizes, int n_in,
                              void* d_out, int out_size, void* d_ws, size_t ws_size,
                              hipStream_t stream) {
    const float* support_feats = (const float*)d_in[0];
    const int* support_masks = (const int*)d_in[1];
    const float* query_feats = (const float*)d_in[2];
    const int* anchor_pos = (const int*)d_in[3];
    const int* anchor_sample = (const int*)d_in[4];
    const int* anchor_radius = (const int*)d_in[5];
    float* out = (float*)d_out;

    float* ws = (float*)d_ws;
    float* ws_partial = ws;                 // S*C = 1536
    float* ws_msum = ws_partial + S_ * C_;  // 64
    float* ws_proto = ws_msum + M_;         // M*C = 24576
    float* ws_v = ws_proto + M_ * C_;       // 384
    float* ws_fg = ws_v + C_;               // 1
    float* ws_dot = ws_fg + 1;              // B*NSLICE*HW = 294912
    float* ws_sq = ws_dot + B_ * NSLICE * HW_;  // 294912

    k_prep<<<REP_P * NB_PREP, 256, 0, stream>>>(support_feats, support_masks, anchor_pos,
                                                anchor_sample, anchor_radius,
                                                ws_partial, ws_proto, ws_msum, ws_fg);
    k_finalize<<<1, 256, 0, stream>>>(ws_partial, ws_msum, ws_proto, ws_fg, ws_v);
    k_score1<<<REP_S * NB_S1, 256, 0, stream>>>(query_feats, ws_v, ws_dot, ws_sq);
    k_score2<<<NB_S2, 256, 0, stream>>>(ws_dot, ws_sq, out);
}

// Round 9
// 98.873 us; speedup vs baseline: 1.7943x; 1.7943x over previous
//
#include <hip/hip_runtime.h>
#include <math.h>

#define S_ 4
#define C_ 384
#define H_ 96
#define W_ 96
#define B_ 8
#define M_ 64
#define HW_ (H_ * W_)
#define EPSV 1e-6f
#define BETA_V 0.3f
#define TEMP_V 0.07f

#define NB_PLANE (S_ * C_)        // 1536 plane blocks
#define NB_PREP (NB_PLANE + M_ + 1)

#define NCH 32                    // channel chunks for score pass 1
#define CCH (C_ / NCH)            // 12 channels per chunk
#define NPART 3                   // pixel thirds
#define PT (HW_ / NPART)          // 3072 px per part
#define NB_S1 (B_ * NCH * NPART)  // 768
#define NB_S2 (B_ * HW_ / 256)    // 288

__device__ __forceinline__ float wave_sum(float v) {
#pragma unroll
    for (int o = 32; o; o >>= 1) v += __shfl_down(v, o, 64);
    return v;
}

__device__ __forceinline__ float block_sum(float v) {
    __shared__ float sm[4];
    int lane = threadIdx.x & 63;
    int wid = threadIdx.x >> 6;
    v = wave_sum(v);
    if (lane == 0) sm[wid] = v;
    __syncthreads();
    float r = sm[0] + sm[1] + sm[2] + sm[3];
    __syncthreads();
    return r;
}

// Prep-v2: role PLANE = one block per (s,c): stage masked plane in LDS,
// compute plane sum (partial) AND all anchor window raw sums from LDS.
// role MSUM = one block per anchor: mask window sum. role FG = mask total.
__global__ __launch_bounds__(256) void k_prep(const float* __restrict__ feats,
                                              const int* __restrict__ mask,
                                              const int* __restrict__ pos,
                                              const int* __restrict__ samp,
                                              const int* __restrict__ rad,
                                              float* __restrict__ partial,
                                              float* __restrict__ praw,
                                              float* __restrict__ msum_out,
                                              float* __restrict__ fg_out) {
    int bid = blockIdx.x;
    int t = threadIdx.x;

    if (bid < NB_PLANE) {
        // ---- PLANE role
        __shared__ float mplane[HW_];  // 36 KB masked plane
        int s = bid / C_;
        int c = bid - s * C_;
        const float4* fp = (const float4*)(feats + (size_t)bid * HW_);
        const int4* mp = (const int4*)(mask + (size_t)s * HW_);
        float acc = 0.0f;
#pragma unroll
        for (int k = 0; k < HW_ / 4 / 256; ++k) {  // 9 iterations
            int i = t + k * 256;
            float4 f = fp[i];
            int4 m = mp[i];
            float4 w;
            w.x = f.x * (float)m.x;
            w.y = f.y * (float)m.y;
            w.z = f.z * (float)m.z;
            w.w = f.w * (float)m.w;
            acc += w.x + w.y + w.z + w.w;
            ((float4*)mplane)[i] = w;
        }
        float tot = block_sum(acc);  // internal barriers also publish mplane
        if (t == 0) partial[bid] = tot;

        // anchor raw window sums from LDS; wave w handles anchors a%4==w
        int wid = t >> 6;
        int lane = t & 63;
        for (int a = wid; a < M_; a += 4) {
            if (samp[a] != s) continue;
            int y = pos[2 * a + 0];
            int x = pos[2 * a + 1];
            int ri = rad[a];
            int r = (ri == 0) ? 4 : (ri == 1) ? 8 : 16;
            int y0 = max(y - r, 0), y1 = min(y + r + 1, H_);
            int x0 = max(x - r, 0), x1 = min(x + r + 1, W_);
            int ww = x1 - x0;
            int n = (y1 - y0) * ww;
            float a2 = 0.0f;
            int yy = lane / ww;
            int xx = lane - yy * ww;
            int dy = 64 / ww, dx = 64 - dy * ww;  // dx < ww
            for (int i = lane; i < n; i += 64) {
                a2 += mplane[(y0 + yy) * W_ + x0 + xx];
                xx += dx; yy += dy;
                if (xx >= ww) { xx -= ww; ++yy; }
            }
            a2 = wave_sum(a2);
            if (lane == 0) praw[a * C_ + c] = a2;
        }
        return;
    }
    bid -= NB_PLANE;
    if (bid < M_) {
        // ---- MSUM role: mask window sum for anchor `bid`
        int a = bid;
        int y = pos[2 * a + 0];
        int x = pos[2 * a + 1];
        int s = samp[a];
        int ri = rad[a];
        int r = (ri == 0) ? 4 : (ri == 1) ? 8 : 16;
        int y0 = max(y - r, 0), y1 = min(y + r + 1, H_);
        int x0 = max(x - r, 0), x1 = min(x + r + 1, W_);
        int ww = x1 - x0;
        int n = (y1 - y0) * ww;
        const int* mp = mask + (size_t)s * HW_;
        float macc = 0.0f;
        int yy = t / ww;
        int xx = t - yy * ww;
        int dy = 256 / ww, dx = 256 - dy * ww;
        for (int i = t; i < n; i += 256) {
            macc += (float)mp[(y0 + yy) * W_ + x0 + xx];
            xx += dx; yy += dy;
            if (xx >= ww) { xx -= ww; ++yy; }
        }
        float ms = block_sum(macc);
        if (t == 0) msum_out[a] = ms;
        return;
    }
    // ---- FG role
    const int4* mp4 = (const int4*)mask;
    float acc = 0.0f;
    for (int i = t; i < S_ * HW_ / 4; i += 256) {
        int4 m = mp4[i];
        acc += (float)(m.x + m.y + m.z + m.w);
    }
    float fg = block_sum(acc);
    if (t == 0) fg_out[0] = fg;
}

// Single block: combine into the final C-vector v, folding /(msum+EPS) into
// the raw window sums (proto[m,c] = praw[m,c] * inv_m, inv_m = 1/(msum+EPS)).
__global__ __launch_bounds__(256) void k_finalize(const float* __restrict__ partial,
                                                  const float* __restrict__ msum,
                                                  const float* __restrict__ praw,
                                                  const float* __restrict__ fg_in,
                                                  float* __restrict__ v) {
    int tid = threadIdx.x;
    int wid = tid >> 6;
    int lane = tid & 63;

    float invfg = 1.0f / (fg_in[0] + EPSV);

    __shared__ float gv[C_];
    for (int c = tid; c < C_; c += 256) {
        float tv = 0.0f;
        for (int s = 0; s < S_; ++s) tv += partial[s * C_ + c];
        gv[c] = tv * invfg;
    }
    __syncthreads();

    float sq = 0.0f;
    for (int c = tid; c < C_; c += 256) sq += gv[c] * gv[c];
    float gn = block_sum(sq);
    gn = fmaxf(sqrtf(gn), 1e-12f);

    float wa = (tid < M_) ? msum[tid] : 0.0f;
    float T = block_sum(wa);
    float wb = (tid < M_) ? msum[tid] / (T + EPSV) : 0.0f;
    float wsum = block_sum(wb);

    // proto norms on proto = praw * inv_m
    __shared__ float pn[M_];
    for (int m = wid; m < M_; m += 4) {
        float im = 1.0f / (msum[m] + EPSV);
        float a = 0.0f;
        for (int c = lane; c < C_; c += 64) {
            float p = praw[m * C_ + c] * im;
            a += p * p;
        }
        a = wave_sum(a);
        if (lane == 0) pn[m] = fmaxf(sqrtf(a), 1e-12f);
    }
    __syncthreads();

    // coefficient on raw values: w_m / pn_m * inv_m
    __shared__ float wq[M_];
    if (tid < M_) {
        float w = (msum[tid] / (T + EPSV)) / (wsum + EPSV);
        wq[tid] = w / pn[tid] * (1.0f / (msum[tid] + EPSV));
    }
    __syncthreads();

    for (int c = tid; c < C_; c += 256) {
        float vl = 0.0f;
        for (int m = 0; m < M_; ++m) vl += wq[m] * praw[m * C_ + c];
        v[c] = BETA_V * (gv[c] / gn) + (1.0f - BETA_V) * vl;
    }
}

// Score pass 1: block = (b, chunk of 12 contiguous channels, pixel third).
// Streams 12 KB-contiguous rows; per-pixel dot/sq partials in registers;
// coalesced float4 partial writes to ws[b][chunk][px].
__global__ __launch_bounds__(256) void k_score1(const float* __restrict__ q,
                                                const float* __restrict__ v,
                                                float* __restrict__ wsd,
                                                float* __restrict__ wss) {
    int bid = blockIdx.x;
    int part = bid % NPART;
    int bc = bid / NPART;
    int ch = bc % NCH;
    int b = bc / NCH;
    int t = threadIdx.x;
    int pxb = part * PT;

    float vcs[CCH];
#pragma unroll
    for (int j = 0; j < CCH; ++j) vcs[j] = v[ch * CCH + j];

    float4 d0 = {0.f, 0.f, 0.f, 0.f}, d1 = d0, d2 = d0;
    float4 s0 = d0, s1 = d0, s2 = d0;
#pragma unroll 2
    for (int j = 0; j < CCH; ++j) {
        int c = ch * CCH + j;
        float vc = vcs[j];
        const float4* qc = (const float4*)(q + ((size_t)b * C_ + c) * HW_ + pxb);
        float4 f0 = qc[0 * 256 + t];
        float4 f1 = qc[1 * 256 + t];
        float4 f2 = qc[2 * 256 + t];
        d0.x += f0.x * vc; d0.y += f0.y * vc; d0.z += f0.z * vc; d0.w += f0.w * vc;
        s0.x += f0.x * f0.x; s0.y += f0.y * f0.y; s0.z += f0.z * f0.z; s0.w += f0.w * f0.w;
        d1.x += f1.x * vc; d1.y += f1.y * vc; d1.z += f1.z * vc; d1.w += f1.w * vc;
        s1.x += f1.x * f1.x; s1.y += f1.y * f1.y; s1.z += f1.z * f1.z; s1.w += f1.w * f1.w;
        d2.x += f2.x * vc; d2.y += f2.y * vc; d2.z += f2.z * vc; d2.w += f2.w * vc;
        s2.x += f2.x * f2.x; s2.y += f2.y * f2.y; s2.z += f2.z * f2.z; s2.w += f2.w * f2.w;
    }

    size_t base = ((size_t)(b * NCH + ch) * HW_ + pxb) / 4;
    float4* od = (float4*)wsd;
    float4* os = (float4*)wss;
    od[base + 0 * 256 + t] = d0;
    od[base + 1 * 256 + t] = d1;
    od[base + 2 * 256 + t] = d2;
    os[base + 0 * 256 + t] = s0;
    os[base + 1 * 256 + t] = s1;
    os[base + 2 * 256 + t] = s2;
}

// Score pass 2: reduce NCH chunk-partials per pixel, write both logit planes.
__global__ __launch_bounds__(256) void k_score2(const float* __restrict__ wsd,
                                                const float* __restrict__ wss,
                                                float* __restrict__ out) {
    int px = blockIdx.x * 256 + threadIdx.x;  // < B_*HW_
    int b = px / HW_;
    int p = px - b * HW_;

    float d = 0.0f, s2 = 0.0f;
#pragma unroll
    for (int ch = 0; ch < NCH; ++ch) {
        size_t idx = (size_t)(b * NCH + ch) * HW_ + p;
        d += wsd[idx];
        s2 += wss[idx];
    }
    float sv = d / fmaxf(sqrtf(s2), 1e-12f);
    float o = sv / TEMP_V;
    float* ob = out + (size_t)b * 2 * HW_;
    ob[p] = -o;
    ob[HW_ + p] = o;
}

extern "C" void kernel_launch(void* const* d_in, const int* in_sizes, int n_in,
                              void* d_out, int out_size, void* d_ws, size_t ws_size,
                              hipStream_t stream) {
    const float* support_feats = (const float*)d_in[0];
    const int* support_masks = (const int*)d_in[1];
    const float* query_feats = (const float*)d_in[2];
    const int* anchor_pos = (const int*)d_in[3];
    const int* anchor_sample = (const int*)d_in[4];
    const int* anchor_radius = (const int*)d_in[5];
    float* out = (float*)d_out;

    float* ws = (float*)d_ws;
    float* ws_partial = ws;                 // S*C = 1536
    float* ws_msum = ws_partial + S_ * C_;  // 64
    float* ws_praw = ws_msum + M_;          // M*C = 24576 (raw window sums)
    float* ws_v = ws_praw + M_ * C_;        // 384
    float* ws_fg = ws_v + C_;               // 1
    float* ws_dot = ws_fg + 1;              // B*NCH*HW = 2359296
    float* ws_sq = ws_dot + (size_t)B_ * NCH * HW_;

    k_prep<<<NB_PREP, 256, 0, stream>>>(support_feats, support_masks, anchor_pos,
                                        anchor_sample, anchor_radius,
                                        ws_partial, ws_praw, ws_msum, ws_fg);
    k_finalize<<<1, 256, 0, stream>>>(ws_partial, ws_msum, ws_praw, ws_fg, ws_v);
    k_score1<<<NB_S1, 256, 0, stream>>>(query_feats, ws_v, ws_dot, ws_sq);
    k_score2<<<NB_S2, 256, 0, stream>>>(ws_dot, ws_sq, out);
}